// Round 4
// baseline (6739.181 us; speedup 1.0000x reference)
//
#include <hip/hip_runtime.h>

typedef float f32x4 __attribute__((ext_vector_type(4)));
typedef __bf16 bf16x8 __attribute__((ext_vector_type(8)));
typedef unsigned short u16;

#define OUTC 4864
#define OUTT ((size_t)63 * OUTC)

__device__ __forceinline__ u16 f2bf(float f) {
    unsigned u = __float_as_uint(f);
    u += 0x7FFFu + ((u >> 16) & 1u);
    return (u16)(u >> 16);
}
__device__ __forceinline__ float bf2f(u16 h) { return __uint_as_float((unsigned)h << 16); }
__device__ __forceinline__ float fexp(float x) { return __expf(x); }
__device__ __forceinline__ float eluf(float x) { return x > 0.f ? x : fexp(x) - 1.f; }
__device__ __forceinline__ float splus(float x) { return x > 15.f ? x : __logf(1.f + fexp(x)); }
__device__ __forceinline__ float sigm(float x) { return 1.f / (1.f + fexp(-x)); }
__device__ __forceinline__ float tanhfast(float x) { return 2.f / (1.f + fexp(-2.f * x)) - 1.f; }
__device__ __forceinline__ int swz(int row, int cb) { return row * 128 + (cb ^ ((row & 7) << 4)); }

// -------- generic NT-tile 64-row MFMA GEMM, depth-2 register prefetch --------
// C[m][n0 + j*nstr + c] = sum_k A[m][k] * Bt[n][k];  requires K >= 128, K % 64 == 0
template <int NT, class FA, class FE>
__device__ __forceinline__ void gemmN(char* As, FA fa, const u16* __restrict__ Bt,
                                      int ldb, int n0, int nstr, int K, int m0, FE fe) {
    char* Bs = As + 8192;
    const int tid = threadIdx.x;
    const int lane = tid & 63;
    const int w = tid >> 6;
    const int wr = (w >> 1) * 32, wc = (w & 1) * 32;
    f32x4 acc[NT][4];
    f32x4 zf = {0.f, 0.f, 0.f, 0.f};
#pragma unroll
    for (int j = 0; j < NT; j++)
#pragma unroll
        for (int q = 0; q < 4; q++) acc[j][q] = zf;
    const int r0 = tid >> 3;
    const int ke = (tid & 7) * 8;
    const int cb = (tid & 7) * 16;
    // ping buffers (even k-iters) / pong buffers (odd)
    uint4 avP0, avP1, bvP[NT][2], avQ0, avQ1, bvQ[NT][2];
    avP0 = fa(m0 + r0, ke);
    avP1 = fa(m0 + r0 + 32, ke);
#pragma unroll
    for (int j = 0; j < NT; j++) {
        bvP[j][0] = *(const uint4*)(Bt + (size_t)(n0 + j * nstr + r0) * ldb + ke);
        bvP[j][1] = *(const uint4*)(Bt + (size_t)(n0 + j * nstr + r0 + 32) * ldb + ke);
    }
    avQ0 = fa(m0 + r0, 64 + ke);
    avQ1 = fa(m0 + r0 + 32, 64 + ke);
#pragma unroll
    for (int j = 0; j < NT; j++) {
        bvQ[j][0] = *(const uint4*)(Bt + (size_t)(n0 + j * nstr + r0) * ldb + 64 + ke);
        bvQ[j][1] = *(const uint4*)(Bt + (size_t)(n0 + j * nstr + r0 + 32) * ldb + 64 + ke);
    }
    bool ping = true;
    for (int k0 = 0; k0 < K; k0 += 64) {
        __syncthreads();
        if (ping) {
            *(uint4*)(As + swz(r0, cb)) = avP0;
            *(uint4*)(As + swz(r0 + 32, cb)) = avP1;
#pragma unroll
            for (int j = 0; j < NT; j++) {
                char* B = Bs + j * 8192;
                *(uint4*)(B + swz(r0, cb)) = bvP[j][0];
                *(uint4*)(B + swz(r0 + 32, cb)) = bvP[j][1];
            }
        } else {
            *(uint4*)(As + swz(r0, cb)) = avQ0;
            *(uint4*)(As + swz(r0 + 32, cb)) = avQ1;
#pragma unroll
            for (int j = 0; j < NT; j++) {
                char* B = Bs + j * 8192;
                *(uint4*)(B + swz(r0, cb)) = bvQ[j][0];
                *(uint4*)(B + swz(r0 + 32, cb)) = bvQ[j][1];
            }
        }
        __syncthreads();
        if (k0 + 128 < K) {
            int k1 = k0 + 128 + ke;
            if (ping) {
                avP0 = fa(m0 + r0, k1);
                avP1 = fa(m0 + r0 + 32, k1);
#pragma unroll
                for (int j = 0; j < NT; j++) {
                    bvP[j][0] = *(const uint4*)(Bt + (size_t)(n0 + j * nstr + r0) * ldb + k1);
                    bvP[j][1] = *(const uint4*)(Bt + (size_t)(n0 + j * nstr + r0 + 32) * ldb + k1);
                }
            } else {
                avQ0 = fa(m0 + r0, k1);
                avQ1 = fa(m0 + r0 + 32, k1);
#pragma unroll
                for (int j = 0; j < NT; j++) {
                    bvQ[j][0] = *(const uint4*)(Bt + (size_t)(n0 + j * nstr + r0) * ldb + k1);
                    bvQ[j][1] = *(const uint4*)(Bt + (size_t)(n0 + j * nstr + r0 + 32) * ldb + k1);
                }
            }
        }
#pragma unroll
        for (int kk = 0; kk < 64; kk += 32) {
            const int fcb = kk * 2 + (lane >> 4) * 16;
            bf16x8 a0 = *(const bf16x8*)(As + swz(wr + (lane & 15), fcb));
            bf16x8 a1 = *(const bf16x8*)(As + swz(wr + 16 + (lane & 15), fcb));
#pragma unroll
            for (int j = 0; j < NT; j++) {
                char* B = Bs + j * 8192;
                bf16x8 b0 = *(const bf16x8*)(B + swz(wc + (lane & 15), fcb));
                bf16x8 b1 = *(const bf16x8*)(B + swz(wc + 16 + (lane & 15), fcb));
                acc[j][0] = __builtin_amdgcn_mfma_f32_16x16x32_bf16(a0, b0, acc[j][0], 0, 0, 0);
                acc[j][1] = __builtin_amdgcn_mfma_f32_16x16x32_bf16(a0, b1, acc[j][1], 0, 0, 0);
                acc[j][2] = __builtin_amdgcn_mfma_f32_16x16x32_bf16(a1, b0, acc[j][2], 0, 0, 0);
                acc[j][3] = __builtin_amdgcn_mfma_f32_16x16x32_bf16(a1, b1, acc[j][3], 0, 0, 0);
            }
        }
        ping = !ping;
    }
    const int er = (lane >> 4) * 4, ec = lane & 15;
#pragma unroll
    for (int q = 0; q < 4; q++) {
        int rr = m0 + wr + (q >> 1) * 16 + er;
        int cc = n0 + wc + (q & 1) * 16 + ec;
#pragma unroll
        for (int r = 0; r < 4; r++) {
            float vals[NT];
#pragma unroll
            for (int j = 0; j < NT; j++) vals[j] = acc[j][q][r];
            fe(rr + r, cc, vals);
        }
    }
}

// -------- prolog: all weight prep + init, one kernel --------
#define PREP_BLOCKS 2048
#define PGSTR (PREP_BLOCKS * 256)
__device__ __forceinline__ void tpose(const float* __restrict__ in, u16* __restrict__ out,
                                      int R, int C, int Rpad, int total, int gtid) {
    for (int i = gtid; i < total; i += PGSTR) {
        int r = i % Rpad;
        int bc = i / Rpad;
        int c = bc % C;
        int bb = bc / C;
        out[i] = (r < R) ? f2bf(in[((size_t)bb * R + r) * C + c]) : (u16)0;
    }
}
__device__ __forceinline__ void castb(const float* __restrict__ in, u16* __restrict__ out,
                                      int total, int gtid) {
    for (int i = gtid; i < total; i += PGSTR) out[i] = f2bf(in[i]);
}

__global__ void __launch_bounds__(256) k_prep(
    const float* W_embed, const float* W_ih, const float* W_hh, const float* W_ens,
    const float* Wp1, const float* Wp2, const float* Wq1, const float* Wq2,
    u16* Wembed_t, u16* Wih_b, u16* Whh_b, u16* Wens_t,
    u16* Wp1_t, u16* Wp2_t, u16* Wq1d_t, u16* Wq1o_t, u16* Wq2_t,
    const float* init_deter, const float* init_stoch, const float* action,
    const float* nonterms, float* deter, u16* h_nt, u16* x_embed) {
    int gtid = blockIdx.x * 256 + threadIdx.x;
    tpose(W_embed, Wembed_t, 288, 1024, 320, 1024 * 320, gtid);
    castb(W_ih, Wih_b, 3072 * 1024, gtid);
    castb(W_hh, Whh_b, 3072 * 1024, gtid);
    tpose(W_ens, Wens_t, 1024, 256, 1024, 5 * 256 * 1024, gtid);
    tpose(Wp1, Wp1_t, 1024, 1024, 1024, 1024 * 1024, gtid);
    tpose(Wp2, Wp2_t, 1024, 512, 1024, 512 * 1024, gtid);
    tpose(Wq1, Wq1d_t, 1024, 1024, 1024, 1024 * 1024, gtid);
    tpose(Wq1 + 1024 * 1024, Wq1o_t, 1024, 1024, 1024, 1024 * 1024, gtid);
    tpose(Wq2, Wq2_t, 1024, 512, 1024, 512 * 1024, gtid);
    for (int idx = gtid; idx < 262144; idx += PGSTR) {
        int b = idx >> 10, d = idx & 1023;
        float nt0 = nonterms[b * 64];
        float dv = init_deter[idx];
        deter[idx] = dv;
        h_nt[idx] = f2bf(dv * nt0);
        if (d < 256) {
            x_embed[b * 320 + d] = f2bf(init_stoch[b * 256 + d] * nt0);
        } else if (d < 320) {
            int c = d - 256;
            x_embed[b * 320 + d] = (c < 32) ? f2bf(action[(size_t)b * 2048 + c] * nt0) : (u16)0;
        }
    }
}

// -------- OBSC precompute (1008 blocks) + gh(0) (192 blocks) --------
__global__ void __launch_bounds__(256) k_obsc_gh0(const float* __restrict__ obs,
                                                  const u16* __restrict__ Wq1o_t,
                                                  u16* __restrict__ OBSC,
                                                  const u16* __restrict__ h_nt,
                                                  const u16* __restrict__ Whh_b,
                                                  const float* __restrict__ b_hh,
                                                  float* __restrict__ gh) {
    __shared__ char sm[40960];
    int bid = blockIdx.x;
    if (bid < 1008) {
        int rb = bid >> 2, cg = bid & 3;
        int m0 = rb * 64, n0 = cg * 256;
        auto fa = [&](int r, int k) {
            int tt = r >> 8, bb = r & 255;
            const float* p = obs + ((size_t)bb * 64 + tt) * 1024 + k;
            float4 f0 = *(const float4*)p, f1 = *(const float4*)(p + 4);
            union { u16 h[8]; uint4 q; } x;
            x.h[0] = f2bf(f0.x); x.h[1] = f2bf(f0.y); x.h[2] = f2bf(f0.z); x.h[3] = f2bf(f0.w);
            x.h[4] = f2bf(f1.x); x.h[5] = f2bf(f1.y); x.h[6] = f2bf(f1.z); x.h[7] = f2bf(f1.w);
            return x.q;
        };
        auto fe = [&](int r, int n, const float* v) {
#pragma unroll
            for (int j = 0; j < 4; j++) OBSC[(size_t)r * 1024 + n + j * 64] = f2bf(v[j]);
        };
        gemmN<4>(sm, fa, Wq1o_t, 1024, n0, 64, 1024, m0, fe);
    } else {
        int j = bid - 1008;
        int m0 = (j / 48) * 64, n0 = (j % 48) * 64;
        auto fa = [&](int r, int k) { return *(const uint4*)(h_nt + r * 1024 + k); };
        auto fe = [&](int r, int n, const float* v) { gh[(size_t)r * 3072 + n] = v[0] + b_hh[n]; };
        gemmN<1>(sm, fa, Whh_b, 1024, n0, 0, 1024, m0, fe);
    }
}

// -------- per-step: sa (64 blocks) --------
__global__ void __launch_bounds__(256) k_sa(const u16* __restrict__ xe,
                                            const u16* __restrict__ Wt,
                                            const float* __restrict__ bias,
                                            u16* __restrict__ sa) {
    __shared__ char sm[16384];
    int m0 = blockIdx.y * 64, n0 = blockIdx.x * 64;
    auto fa = [&](int r, int k) { return *(const uint4*)(xe + r * 320 + k); };
    auto fe = [&](int r, int n, const float* v) {
        sa[r * 1024 + n] = f2bf(eluf(v[0] + bias[n]));
    };
    gemmN<1>(sm, fa, Wt, 320, n0, 0, 320, m0, fe);
}

// -------- per-step: gi GEMM (NT=3 over gates) + fused GRU epilogue (64 blocks) --------
__global__ void __launch_bounds__(256) k_gi_gru(const u16* __restrict__ sa,
                                                const u16* __restrict__ Wih_b,
                                                const float* __restrict__ b_ih,
                                                const float* __restrict__ gh,
                                                const float* __restrict__ nonterms,
                                                float* __restrict__ deter,
                                                u16* __restrict__ deter_hist,
                                                u16* __restrict__ h_nt,
                                                float* __restrict__ out, int t) {
    __shared__ char sm[32768];
    int m0 = blockIdx.y * 64, n0 = blockIdx.x * 64;   // n0 = d-tile
    auto fa = [&](int r, int k) { return *(const uint4*)(sa + r * 1024 + k); };
    auto fe = [&](int r, int d, const float* v) {
        size_t gb = (size_t)r * 3072;
        float rg = sigm(v[0] + b_ih[d] + gh[gb + d]);
        float zg = sigm(v[1] + b_ih[1024 + d] + gh[gb + 1024 + d]);
        float ng = tanhfast(v[2] + b_ih[2048 + d] + rg * gh[gb + 2048 + d]);
        float h = deter[r * 1024 + d] * nonterms[r * 64 + t];
        float dn = (1.f - zg) * ng + zg * h;
        deter[r * 1024 + d] = dn;
        deter_hist[(size_t)t * 262144 + r * 1024 + d] = f2bf(dn);
        h_nt[r * 1024 + d] = f2bf(dn * nonterms[r * 64 + t + 1]);
        float* ob = out + (size_t)r * OUTT + (size_t)t * OUTC;
        ob[768 + d] = dn;
        ob[2560 + d] = dn;
    };
    gemmN<3>(sm, fa, Wih_b, 1024, n0, 1024, 1024, m0, fe);
}

// -------- per-step: gh(t+1) (192 blocks) || HQ (64 blocks) --------
__global__ void __launch_bounds__(256) k_step3(const u16* __restrict__ h_nt,
                                               const u16* __restrict__ Whh_b,
                                               const float* __restrict__ b_hh,
                                               float* __restrict__ gh,
                                               const u16* __restrict__ deter_hist,
                                               const u16* __restrict__ Wq1d_t,
                                               const float* __restrict__ bq1,
                                               const u16* __restrict__ OBSC,
                                               u16* __restrict__ HQ, int t) {
    __shared__ char sm[16384];
    int bid = blockIdx.x;
    if (bid < 192) {
        if (t >= 62) return;
        int m0 = (bid / 48) * 64, n0 = (bid % 48) * 64;
        auto fa = [&](int r, int k) { return *(const uint4*)(h_nt + r * 1024 + k); };
        auto fe = [&](int r, int n, const float* v) { gh[(size_t)r * 3072 + n] = v[0] + b_hh[n]; };
        gemmN<1>(sm, fa, Whh_b, 1024, n0, 0, 1024, m0, fe);
    } else {
        int j = bid - 192;
        int m0 = (j / 16) * 64, n0 = (j % 16) * 64;
        const u16* A = deter_hist + (size_t)t * 262144;
        const u16* ob = OBSC + (size_t)t * 262144;
        auto fa = [&](int r, int k) { return *(const uint4*)(A + r * 1024 + k); };
        auto fe = [&](int r, int n, const float* v) {
            HQ[r * 1024 + n] = f2bf(eluf(v[0] + bq1[n] + bf2f(ob[r * 1024 + n])));
        };
        gemmN<1>(sm, fa, Wq1d_t, 1024, n0, 0, 1024, m0, fe);
    }
}

// -------- per-step: q2 + post sampling + x_embed (20 blocks) --------
__global__ void __launch_bounds__(256) k_q2dist(const u16* __restrict__ HQ,
                                                const u16* __restrict__ Wq2_t,
                                                const float* __restrict__ bq2,
                                                const float* __restrict__ noise_q,
                                                const float* __restrict__ nonterms,
                                                const float* __restrict__ action,
                                                float* __restrict__ out,
                                                u16* __restrict__ x_embed, int t) {
    __shared__ char sm[24576];
    int bid = blockIdx.x;
    if (bid < 16) {
        int m0 = (bid >> 2) * 64, n0 = (bid & 3) * 64;
        auto fa = [&](int r, int k) { return *(const uint4*)(HQ + r * 1024 + k); };
        auto fe = [&](int r, int s, const float* v) {
            float m = v[0] + bq2[s];
            float sd = splus(v[1] + bq2[s + 256]) + 0.1f;
            float eps = noise_q[(size_t)t * 65536 + r * 256 + s];
            float st = m + sd * eps;
            float* obp = out + (size_t)r * OUTT + (size_t)t * OUTC + 1792;
            obp[s] = m;
            obp[256 + s] = sd;
            obp[512 + s] = st;
            float ntn = nonterms[r * 64 + t + 1];
            x_embed[r * 320 + s] = f2bf(st * ntn);
        };
        gemmN<2>(sm, fa, Wq2_t, 1024, n0, 256, 1024, m0, fe);
    } else {
        for (int i = (bid - 16) * 256 + threadIdx.x; i < 16384; i += 1024) {
            int b = i >> 6, c = i & 63;
            float ntn = nonterms[b * 64 + t + 1];
            u16 v = 0;
            if (c < 32) v = f2bf(action[(size_t)b * 2048 + (size_t)(t + 1) * 32 + c] * ntn);
            x_embed[b * 320 + 256 + c] = v;
        }
    }
}

// -------- batched epilogues (M = 16128) --------
__global__ void __launch_bounds__(256) k_ens(const u16* __restrict__ sa_hist,
                                             const u16* __restrict__ Wens_t,
                                             const float* __restrict__ b_ens,
                                             float* __restrict__ out) {
    __shared__ char sm[40960];
    int m0 = blockIdx.y * 64, n0 = blockIdx.x * 256;
    auto fa = [&](int r, int k) { return *(const uint4*)(sa_hist + (size_t)r * 1024 + k); };
    auto fe = [&](int r, int cc, const float* v) {
        int tt = r >> 8, b = r & 255;
        float* op = out + (size_t)b * OUTT + (size_t)tt * OUTC + 3584;
#pragma unroll
        for (int j = 0; j < 4; j++) {
            int n = cc + j * 64;
            op[n] = v[j] + b_ens[n];
        }
    };
    gemmN<4>(sm, fa, Wens_t, 1024, n0, 64, 1024, m0, fe);
}

__global__ void __launch_bounds__(256) k_hp(const u16* __restrict__ deter_hist,
                                            const u16* __restrict__ Wp1_t,
                                            const float* __restrict__ bp1,
                                            u16* __restrict__ HP) {
    __shared__ char sm[40960];
    int m0 = blockIdx.y * 64, n0 = blockIdx.x * 256;
    auto fa = [&](int r, int k) { return *(const uint4*)(deter_hist + (size_t)r * 1024 + k); };
    auto fe = [&](int r, int cc, const float* v) {
#pragma unroll
        for (int j = 0; j < 4; j++) {
            int n = cc + j * 64;
            HP[(size_t)r * 1024 + n] = f2bf(eluf(v[j] + bp1[n]));
        }
    };
    gemmN<4>(sm, fa, Wp1_t, 1024, n0, 64, 1024, m0, fe);
}

__global__ void __launch_bounds__(256) k_p2(const u16* __restrict__ HP,
                                            const u16* __restrict__ Wp2_t,
                                            const float* __restrict__ bp2,
                                            const float* __restrict__ noise_p,
                                            float* __restrict__ out) {
    __shared__ char sm[24576];
    int m0 = blockIdx.y * 64, n0 = blockIdx.x * 64;
    auto fa = [&](int r, int k) { return *(const uint4*)(HP + (size_t)r * 1024 + k); };
    auto fe = [&](int r, int s, const float* v) {
        int tt = r >> 8, b = r & 255;
        float m = v[0] + bp2[s];
        float sd = splus(v[1] + bp2[s + 256]) + 0.1f;
        float eps = noise_p[(size_t)tt * 65536 + b * 256 + s];
        float st = m + sd * eps;
        float* obp = out + (size_t)b * OUTT + (size_t)tt * OUTC;
        obp[s] = m;
        obp[256 + s] = sd;
        obp[512 + s] = st;
    };
    gemmN<2>(sm, fa, Wp2_t, 1024, n0, 256, 1024, m0, fe);
}

// ---------------- host ----------------
extern "C" void kernel_launch(void* const* d_in, const int* in_sizes, int n_in,
                              void* d_out, int out_size, void* d_ws, size_t ws_size,
                              hipStream_t stream) {
    const float* obs = (const float*)d_in[1];
    const float* action = (const float*)d_in[2];
    const float* nonterms = (const float*)d_in[3];
    const float* init_deter = (const float*)d_in[4];
    const float* init_stoch = (const float*)d_in[5];
    const float* noise_p = (const float*)d_in[6];
    const float* noise_q = (const float*)d_in[7];
    const float* W_embed = (const float*)d_in[8];
    const float* b_embed = (const float*)d_in[9];
    const float* W_ens = (const float*)d_in[10];
    const float* b_ens = (const float*)d_in[11];
    const float* W_ih = (const float*)d_in[12];
    const float* W_hh = (const float*)d_in[13];
    const float* b_ih = (const float*)d_in[14];
    const float* b_hh = (const float*)d_in[15];
    const float* Wp1 = (const float*)d_in[16];
    const float* bp1 = (const float*)d_in[17];
    const float* Wp2 = (const float*)d_in[18];
    const float* bp2 = (const float*)d_in[19];
    const float* Wq1 = (const float*)d_in[20];
    const float* bq1 = (const float*)d_in[21];
    const float* Wq2 = (const float*)d_in[22];
    const float* bq2 = (const float*)d_in[23];
    float* out = (float*)d_out;

    char* ws = (char*)d_ws;
    size_t off = 0;
    auto alloc = [&](size_t bytes) {
        void* p = ws + off;
        off += (bytes + 255) & ~(size_t)255;
        return p;
    };
    u16* Wembed_t = (u16*)alloc((size_t)1024 * 320 * 2);
    u16* Wih_b = (u16*)alloc((size_t)3072 * 1024 * 2);
    u16* Whh_b = (u16*)alloc((size_t)3072 * 1024 * 2);
    u16* Wens_t = (u16*)alloc((size_t)1280 * 1024 * 2);
    u16* Wp1_t = (u16*)alloc((size_t)1024 * 1024 * 2);
    u16* Wp2_t = (u16*)alloc((size_t)512 * 1024 * 2);
    u16* Wq1d_t = (u16*)alloc((size_t)1024 * 1024 * 2);
    u16* Wq1o_t = (u16*)alloc((size_t)1024 * 1024 * 2);
    u16* Wq2_t = (u16*)alloc((size_t)512 * 1024 * 2);
    u16* OBSC = (u16*)alloc((size_t)16128 * 1024 * 2);  // reused as HP in epilogue
    u16* sa_hist = (u16*)alloc((size_t)16128 * 1024 * 2);
    u16* deter_hist = (u16*)alloc((size_t)16128 * 1024 * 2);
    u16* x_embed = (u16*)alloc((size_t)256 * 320 * 2);
    u16* h_nt = (u16*)alloc((size_t)256 * 1024 * 2);
    u16* HQ = (u16*)alloc((size_t)256 * 1024 * 2);
    float* deter = (float*)alloc((size_t)256 * 1024 * 4);
    float* gh = (float*)alloc((size_t)256 * 3072 * 4);
    (void)ws_size; (void)in_sizes; (void)n_in; (void)out_size;

    k_prep<<<PREP_BLOCKS, 256, 0, stream>>>(
        W_embed, W_ih, W_hh, W_ens, Wp1, Wp2, Wq1, Wq2,
        Wembed_t, Wih_b, Whh_b, Wens_t, Wp1_t, Wp2_t, Wq1d_t, Wq1o_t, Wq2_t,
        init_deter, init_stoch, action, nonterms, deter, h_nt, x_embed);
    k_obsc_gh0<<<1200, 256, 0, stream>>>(obs, Wq1o_t, OBSC, h_nt, Whh_b, b_hh, gh);

    for (int t = 0; t < 63; t++) {
        u16* sa_t = sa_hist + (size_t)t * 262144;
        k_sa<<<dim3(16, 4), 256, 0, stream>>>(x_embed, Wembed_t, b_embed, sa_t);
        k_gi_gru<<<dim3(16, 4), 256, 0, stream>>>(sa_t, Wih_b, b_ih, gh, nonterms,
                                                  deter, deter_hist, h_nt, out, t);
        k_step3<<<256, 256, 0, stream>>>(h_nt, Whh_b, b_hh, gh, deter_hist, Wq1d_t,
                                         bq1, OBSC, HQ, t);
        k_q2dist<<<20, 256, 0, stream>>>(HQ, Wq2_t, bq2, noise_q, nonterms, action,
                                         out, x_embed, t);
    }

    k_ens<<<dim3(5, 252), 256, 0, stream>>>(sa_hist, Wens_t, b_ens, out);
    u16* HP = OBSC;  // reuse
    k_hp<<<dim3(4, 252), 256, 0, stream>>>(deter_hist, Wp1_t, bp1, HP);
    k_p2<<<dim3(4, 252), 256, 0, stream>>>(HP, Wp2_t, bp2, noise_p, out);
}